// Round 19
// baseline (101.296 us; speedup 1.0000x reference)
//
#include <hip/hip_runtime.h>
#include <hip/hip_bf16.h>
#include <math.h>

#define BB 32
#define NN 102400
#define TT 64
#define SS 1600
#define K3N (3 * NN)          // 307200
#define GEMB 600              // gemm blocks = 8 b-groups x 75 k-segments
#define NSEG 75
#define SEGK 4096             // k per segment
#define SSTEP 128             // k per superstep (w LDS chunk)
#define NSS (SEGK / SSTEP)    // 32 supersteps
#define CPB 512               // hi-channel copy blocks
#define PI_F 3.14159265358979323846f

#define AS1 __attribute__((address_space(1)))
#define AS3 __attribute__((address_space(3)))

// async 16B-per-lane global->LDS DMA. LDS dest = wave-uniform base + lane*16 (HW).
__device__ __forceinline__ void gload16(const float* g, float* l) {
    __builtin_amdgcn_global_load_lds((const AS1 void*)g, (AS3 void*)l, 16, 0, 0);
}

// ---------------- K1 mega-kernel:
//   blocks [0, GEMB)      : GEMM1 partials, STREAM-MINIMIZED partition:
//       block = (bgp = g/75, seg = g%75); 4 b-rows x 4096 k. Each wave owns ONE
//       b-row, streamed sequentially (16KB contiguous, float2/lane/superstep)
//       -> 2400 chip-wide x-streams (was 16K; copy's 512 streams run 4.6TB/s).
//       w stripe staged per 128k superstep (16KB dbuf, R17 rotated rows, 2-way
//       banks); 8 b-groups re-read each stripe -> L3-absorbed.
//       Lane: 2k x 32c, acc[32], 64-way k-split, 6-shfl epilogue.
//   blocks [GEMB, +CPB)   : copy channels 3..5 x->out
//   blocks [GEMB+CPB,+TT) : pts1
__global__ __launch_bounds__(256) void k1_mega(const float* __restrict__ x,
                                               const float* __restrict__ w1,
                                               const float* __restrict__ A,
                                               const int* __restrict__ tess,
                                               float* __restrict__ h_part,
                                               float* __restrict__ out,
                                               float* __restrict__ pts1) {
    __shared__ float wls[2][SSTEP * 32];   // 2 x 16KB: [k][(c+rot)&31]
    const int tid = threadIdx.x;
    if (blockIdx.x < GEMB) {
        const int lane = tid & 63, wv = tid >> 6;
        const int bgp = blockIdx.x / NSEG;
        const int seg = blockIdx.x - bgp * NSEG;
        const int b = bgp * 4 + wv;          // this wave's batch row
        const int K0 = seg * SEGK;
        const int rot = (lane >> 1) & 7;     // row-rotation for this lane's rows

        // w staging: 4 calls per wave; call n covers 16B-slots [(wv*4+n)*64 + lane]
        size_t gw[4]; int lw[4];
        #pragma unroll
        for (int n = 0; n < 4; ++n) {
            const int s = (wv * 4 + n) * 64 + lane;
            const int k = s >> 3, p = s & 7;
            gw[n] = (size_t)k * 32 + (((p - ((k >> 2) & 7)) & 7) * 4);
            lw[n] = (wv * 4 + n) * 256;
        }

        float acc[32];
        #pragma unroll
        for (int c = 0; c < 32; ++c) acc[c] = 0.f;

        const float* xrow = x + (size_t)b * 6 * NN + K0;

        {   // prologue: stage superstep 0 w into buffer 0
            #pragma unroll
            for (int n = 0; n < 4; ++n)
                gload16(w1 + gw[n] + (size_t)K0 * 32, &wls[0][lw[n]]);
        }
        float2 xcur = *(const float2*)(xrow + lane * 2);
        __syncthreads();   // drains vmcnt(0): buffer 0 ready

        int cur = 0;
        for (int s = 0; s < NSS; ++s) {
            float2 xnext;
            if (s + 1 < NSS) {   // next superstep's DMA + x-load fly under compute
                const int k0n = K0 + (s + 1) * SSTEP;
                const int nb = cur ^ 1;
                #pragma unroll
                for (int n = 0; n < 4; ++n)
                    gload16(w1 + gw[n] + (size_t)k0n * 32, &wls[nb][lw[n]]);
                xnext = *(const float2*)(xrow + (s + 1) * SSTEP + lane * 2);
            }
            const float* wc = wls[cur];
            #pragma unroll
            for (int kk = 0; kk < 2; ++kk) {
                const int r = lane * 2 + kk;
                const float xj = kk ? xcur.y : xcur.x;
                const float* wrow = wc + r * 32;
                #pragma unroll
                for (int q = 0; q < 8; ++q) {
                    const float4 w = *(const float4*)(wrow + ((q + rot) & 7) * 4);
                    acc[q * 4 + 0] = fmaf(xj, w.x, acc[q * 4 + 0]);
                    acc[q * 4 + 1] = fmaf(xj, w.y, acc[q * 4 + 1]);
                    acc[q * 4 + 2] = fmaf(xj, w.z, acc[q * 4 + 2]);
                    acc[q * 4 + 3] = fmaf(xj, w.w, acc[q * 4 + 3]);
                }
            }
            __syncthreads();   // next buf staged + all reads of cur done
            cur ^= 1;
            xcur = xnext;
        }

        // 64-way k-split reduce across the wave (all lanes end with full sums)
        #pragma unroll
        for (int off = 1; off < 64; off <<= 1) {
            #pragma unroll
            for (int c = 0; c < 32; ++c)
                acc[c] += __shfl_xor(acc[c], off, 64);
        }
        if (lane == 0) {
            float* hp = h_part + (size_t)blockIdx.x * 128 + wv * 32;
            #pragma unroll
            for (int q = 0; q < 8; ++q) {
                float4 v;
                v.x = acc[q * 4 + 0]; v.y = acc[q * 4 + 1];
                v.z = acc[q * 4 + 2]; v.w = acc[q * 4 + 3];
                *(float4*)(hp + q * 4) = v;
            }
        }
    } else if (blockIdx.x < GEMB + CPB) {
        // ---- hi-channel copy: 32 b x 307200 floats = 2457600 float4
        const int cb = blockIdx.x - GEMB;
        for (int i = cb * 256 + tid; i < 2457600; i += CPB * 256) {
            const int b = i / 76800;              // 76800 = 307200/4
            const int rem = i - b * 76800;
            const size_t off = (size_t)b * (6 * NN) + K3N + (size_t)rem * 4;
            *(float4*)(out + off) = *(const float4*)(x + off);
        }
    } else {
        // ---- pts1[t][j] = mean_s A[j][tess[t,s]]
        const int t = blockIdx.x - GEMB - CPB;
        const int* tr = tess + t * SS;
        float s0 = 0.f, s1 = 0.f, s2 = 0.f;
        for (int s = tid; s < SS; s += 256) {
            const int idx = tr[s];
            s0 += A[idx]; s1 += A[NN + idx]; s2 += A[2 * NN + idx];
        }
        #pragma unroll
        for (int o = 32; o > 0; o >>= 1) {
            s0 += __shfl_down(s0, o, 64);
            s1 += __shfl_down(s1, o, 64);
            s2 += __shfl_down(s2, o, 64);
        }
        __shared__ float red[4 * 3];
        const int lane = tid & 63, wv = tid >> 6;
        if (lane == 0) { red[wv * 3] = s0; red[wv * 3 + 1] = s1; red[wv * 3 + 2] = s2; }
        __syncthreads();
        if (tid < 3) {
            const float s = red[tid] + red[3 + tid] + red[6 + tid] + red[9 + tid];
            pts1[t * 3 + tid] = s * (1.0f / SS);
        }
    }
}

// ---------------- KB: h-reduce + rigid params, 32 blocks (one per b)
__global__ __launch_bounds__(256) void kb_rigid(const float* __restrict__ h_part,
                                                const float* __restrict__ b1,
                                                const float* __restrict__ w2,
                                                const float* __restrict__ b2,
                                                const float* __restrict__ sz,
                                                float* __restrict__ RT) {
    const int bb = blockIdx.x;
    __shared__ float part[8][32];
    __shared__ float hsh[32];
    const int c = threadIdx.x & 31, g = threadIdx.x >> 5;
    float s = 0.f;
    const size_t base = (size_t)(bb >> 2) * NSEG * 128 + (bb & 3) * 32;
    for (int j = g; j < NSEG; j += 8) s += h_part[base + (size_t)j * 128 + c];
    part[g][c] = s;
    __syncthreads();
    if (threadIdx.x < 32) {
        float acc = 0.f;
        #pragma unroll
        for (int g2 = 0; g2 < 8; ++g2) acc += part[g2][threadIdx.x];
        hsh[threadIdx.x] = fmaxf(acc + b1[threadIdx.x], 0.f);
    }
    __syncthreads();
    const int t = threadIdx.x;
    if (t < TT) {
        float z[3];
        #pragma unroll
        for (int j = 0; j < 3; ++j) {
            const int col = 6 * t + 3 + j;
            float s2 = b2[col];
            #pragma unroll 8
            for (int cc = 0; cc < 32; ++cc) s2 = fmaf(hsh[cc], w2[cc * 384 + col], s2);
            z[j] = tanhf(s2);
        }
        float c0, s0, c1, s1, c2, s2v;
        sincosf(PI_F * z[0], &s0, &c0);
        sincosf(PI_F * z[1], &s1, &c1);
        sincosf(PI_F * z[2], &s2v, &c2);
        const float R00 = c0 * c1;
        const float R01 = -s0 * c2 + c0 * s1 * s2v;
        const float R02 = s0 * s2v + c0 * s1 * c2;
        const float R10 = s0 * c1;
        const float R11 = c0 * c2 + s0 * s1 * s2v;
        const float R12 = -c0 * s2v + s0 * s1 * c2;
        const float R20 = -s1;
        const float R21 = c1 * s2v;
        const float R22 = c1 * c2;
        const float szx = sz[0], szy = sz[1], szz = sz[2];
        const float cx = 0.5f * szx, cy = 0.5f * szy, cz = 0.5f * szz;
        const float T0 = z[0] * szx + cx - (cx * R00 + cy * R10 + cz * R20);
        const float T1 = z[1] * szy + cy - (cx * R01 + cy * R11 + cz * R21);
        const float T2 = z[2] * szz + cz - (cx * R02 + cy * R12 + cz * R22);
        float* o = RT + (bb * TT + t) * 12;
        o[0] = R00; o[1] = R10; o[2]  = R20; o[3]  = T0;
        o[4] = R01; o[5] = R11; o[6]  = R21; o[7]  = T1;
        o[8] = R02; o[9] = R12; o[10] = R22; o[11] = T2;
    }
}

// ---------------- K3: transform + scatter + pts2
__global__ __launch_bounds__(256) void k3_transform(const float* __restrict__ x,
                                                    const int* __restrict__ tess,
                                                    const float* __restrict__ RT,
                                                    float* __restrict__ out,
                                                    float* __restrict__ pts2) {
    const int blk = blockIdx.x;
    const int b = blk / TT, t = blk % TT;
    const float* p = RT + blk * 12;
    const float M00 = p[0], M01 = p[1], M02 = p[2], T0 = p[3];
    const float M10 = p[4], M11 = p[5], M12 = p[6], T1 = p[7];
    const float M20 = p[8], M21 = p[9], M22 = p[10], T2 = p[11];
    const float* xb = x + (size_t)b * 6 * NN;
    float* ob = out + (size_t)b * 6 * NN;
    const int* tr = tess + t * SS;
    float s0 = 0.f, s1 = 0.f, s2 = 0.f;
    for (int s = threadIdx.x; s < SS; s += 256) {
        const int idx = tr[s];
        const float x0 = xb[idx], x1 = xb[NN + idx], x2 = xb[2 * NN + idx];
        const float y0 = fmaf(M00, x0, fmaf(M01, x1, fmaf(M02, x2, T0)));
        const float y1 = fmaf(M10, x0, fmaf(M11, x1, fmaf(M12, x2, T1)));
        const float y2 = fmaf(M20, x0, fmaf(M21, x1, fmaf(M22, x2, T2)));
        ob[idx] = y0; ob[NN + idx] = y1; ob[2 * NN + idx] = y2;
        s0 += y0; s1 += y1; s2 += y2;
    }
    #pragma unroll
    for (int o = 32; o > 0; o >>= 1) {
        s0 += __shfl_down(s0, o, 64);
        s1 += __shfl_down(s1, o, 64);
        s2 += __shfl_down(s2, o, 64);
    }
    __shared__ float red[4 * 3];
    const int lane = threadIdx.x & 63, wv = threadIdx.x >> 6;
    if (lane == 0) { red[wv * 3] = s0; red[wv * 3 + 1] = s1; red[wv * 3 + 2] = s2; }
    __syncthreads();
    if (threadIdx.x < 3) {
        const float s = red[threadIdx.x] + red[3 + threadIdx.x] + red[6 + threadIdx.x] + red[9 + threadIdx.x];
        pts2[blk * 3 + threadIdx.x] = s * (1.0f / SS);
    }
}

// ---------------- K5: reg[b] = sum_{t,u} (mask[t,u]*(d1[t,u]-d2[b,t,u]))^2
__global__ __launch_bounds__(256) void k5_reg(const float* __restrict__ pts1,
                                              const float* __restrict__ pts2,
                                              const float* __restrict__ mask,
                                              float* __restrict__ out) {
    const int b = blockIdx.x;
    __shared__ float p1[TT * 3], p2[TT * 3];
    for (int i = threadIdx.x; i < TT * 3; i += 256) {
        p1[i] = pts1[i];
        p2[i] = pts2[b * TT * 3 + i];
    }
    __syncthreads();
    float acc = 0.f;
    for (int pr = threadIdx.x; pr < TT * TT; pr += 256) {
        const int t = pr >> 6, u = pr & 63;
        float dx = p1[t * 3] - p1[u * 3];
        float dy = p1[t * 3 + 1] - p1[u * 3 + 1];
        float dz = p1[t * 3 + 2] - p1[u * 3 + 2];
        const float d1 = sqrtf(dx * dx + dy * dy + dz * dz + 1e-12f);
        dx = p2[t * 3] - p2[u * 3];
        dy = p2[t * 3 + 1] - p2[u * 3 + 1];
        dz = p2[t * 3 + 2] - p2[u * 3 + 2];
        const float d2 = sqrtf(dx * dx + dy * dy + dz * dz + 1e-12f);
        const float d = mask[pr] * (d1 - d2);
        acc = fmaf(d, d, acc);
    }
    #pragma unroll
    for (int o = 32; o > 0; o >>= 1) acc += __shfl_down(acc, o, 64);
    __shared__ float red[4];
    const int lane = threadIdx.x & 63, wv = threadIdx.x >> 6;
    if (lane == 0) red[wv] = acc;
    __syncthreads();
    if (threadIdx.x == 0) {
        out[(size_t)BB * 6 * NN + b] = red[0] + red[1] + red[2] + red[3];
    }
}

extern "C" void kernel_launch(void* const* d_in, const int* in_sizes, int n_in,
                              void* d_out, int out_size, void* d_ws, size_t ws_size,
                              hipStream_t stream) {
    const float* x    = (const float*)d_in[0];
    const float* w1   = (const float*)d_in[1];
    const float* b1   = (const float*)d_in[2];
    const float* w2   = (const float*)d_in[3];
    const float* b2   = (const float*)d_in[4];
    const float* A    = (const float*)d_in[5];
    const float* mask = (const float*)d_in[6];
    const float* sz   = (const float*)d_in[7];
    const int*   tess = (const int*)d_in[8];
    float* out = (float*)d_out;
    float* ws  = (float*)d_ws;

    float* h_part = ws;                           // GEMB*128 = 76800 floats
    float* RT     = h_part + (size_t)GEMB * 128;  // 2048*12
    float* pts2   = RT + BB * TT * 12;            // 2048*3
    float* pts1   = pts2 + BB * TT * 3;           // 64*3

    k1_mega<<<GEMB + CPB + TT, 256, 0, stream>>>(x, w1, A, tess, h_part, out, pts1);
    kb_rigid<<<BB, 256, 0, stream>>>(h_part, b1, w2, b2, sz, RT);
    k3_transform<<<BB * TT, 256, 0, stream>>>(x, tess, RT, out, pts2);
    k5_reg<<<BB, 256, 0, stream>>>(pts1, pts2, mask, out);
}

// Round 20
// 74.363 us; speedup vs baseline: 1.3622x; 1.3622x over previous
//
#include <hip/hip_runtime.h>
#include <hip/hip_bf16.h>
#include <math.h>

#define BB 32
#define NN 102400
#define TT 64
#define SS 1600
#define K3N (3 * NN)          // 307200
#define KC 64                 // K-chunk for GEMM1
#define G1 512                // gemm blocks (2/CU, copy co-resident)
#define CPB 512               // hi-channel copy blocks
#define NCHUNK (K3N / KC)     // 4800
#define PI_F 3.14159265358979323846f

#define AS1 __attribute__((address_space(1)))
#define AS3 __attribute__((address_space(3)))

// async 16B-per-lane global->LDS DMA. LDS dest = wave-uniform base + lane*16 (HW).
__device__ __forceinline__ void gload16(const float* g, float* l) {
    __builtin_amdgcn_global_load_lds((const AS1 void*)g, (AS3 void*)l, 16, 0, 0);
}

// ---------------- K1 mega-kernel (R12 configuration — measured best, 74.4 us):
//   blocks [0, G1)        : GEMM1 partials via global_load_lds double-buffer.
//       LDS linear; conflicts tamed by pre-swizzled GLOBAL source:
//       x quads XOR b&7, w octets XOR k&3.
//   blocks [G1, G1+CPB)   : copy channels 3..5 x->out (co-resident with gemm)
//   blocks [G1+CPB, +TT)  : pts1
__global__ __launch_bounds__(256) void k1_mega(const float* __restrict__ x,
                                               const float* __restrict__ w1,
                                               const float* __restrict__ A,
                                               const int* __restrict__ tess,
                                               float* __restrict__ h_part,
                                               float* __restrict__ out,
                                               float* __restrict__ pts1) {
    __shared__ float xs[2][32 * 64];    // 8 KB per buffer: [b][quad^swz]
    __shared__ float wls[2][64 * 32];   // 8 KB per buffer: [k][octet^swz]
    const int tid = threadIdx.x;
    if (blockIdx.x < G1) {
        const int lane = tid & 63, wv = tid >> 6;
        const int ks = tid & 7;              // k = k0 + ks + 8i
        const int bg = (tid >> 3) & 7;       // b = bg + 8j
        const int cg = wv;                   // c-octet
        // staging slot assignment: call n of wave wv covers 16B-slots [(wv*2+n)*64 + lane]
        const int sA = (wv * 2 + 0) * 64 + lane;
        const int sB = (wv * 2 + 1) * 64 + lane;
        // x: slot s -> (b = s>>4, q = s&15); content = x[b][k0 + 4*(q ^ (b&7)) ..+3]
        const int xbA = sA >> 4, xqA = sA & 15;
        const int xbB = sB >> 4, xqB = sB & 15;
        const size_t gxA = (size_t)xbA * 6 * NN + 4 * (xqA ^ (xbA & 7));
        const size_t gxB = (size_t)xbB * 6 * NN + 4 * (xqB ^ (xbB & 7));
        // w: slot s -> (k = s>>3, p = s&7); content = w1[k0+k][((p>>1)^(k&3))*8 + (p&1)*4 ..+3]
        const int kA = sA >> 3, pA = sA & 7;
        const int kB = sB >> 3, pB = sB & 7;
        const size_t gwA = (size_t)kA * 32 + (((pA >> 1) ^ (kA & 3)) * 8 + (pA & 1) * 4);
        const size_t gwB = (size_t)kB * 32 + (((pB >> 1) ^ (kB & 3)) * 8 + (pB & 1) * 4);
        const int lA = (wv * 2 + 0) * 256;   // uniform LDS float-offset of call A
        const int lB = (wv * 2 + 1) * 256;

        float acc[4][8];
        #pragma unroll
        for (int j = 0; j < 4; ++j)
            #pragma unroll
            for (int c = 0; c < 8; ++c) acc[j][c] = 0.f;

        const int start = (int)(((long)blockIdx.x * NCHUNK) / G1);
        const int end   = (int)(((long)(blockIdx.x + 1) * NCHUNK) / G1);

        {   // prologue: stage chunk `start` into buffer 0
            const int k0 = start * KC;
            gload16(x + gxA + k0, &xs[0][lA]);
            gload16(x + gxB + k0, &xs[0][lB]);
            gload16(w1 + gwA + (size_t)k0 * 32, &wls[0][lA]);
            gload16(w1 + gwB + (size_t)k0 * 32, &wls[0][lB]);
        }
        __syncthreads();   // drains vmcnt(0): buffer 0 ready

        int cur = 0;
        for (int chunk = start; chunk < end; ++chunk) {
            if (chunk + 1 < end) {   // issue next chunk's DMA — flies under compute
                const int k0 = (chunk + 1) * KC;
                const int nb = cur ^ 1;
                gload16(x + gxA + k0, &xs[nb][lA]);
                gload16(x + gxB + k0, &xs[nb][lB]);
                gload16(w1 + gwA + (size_t)k0 * 32, &wls[nb][lA]);
                gload16(w1 + gwB + (size_t)k0 * 32, &wls[nb][lB]);
            }
            const float* xc = xs[cur];
            const float* wc = wls[cur];
            #pragma unroll
            for (int i = 0; i < 8; ++i) {
                const int k = ks + 8 * i;
                const int xq = ((k >> 2) ^ bg) * 4 + (k & 3);   // b&7 == bg for all j
                const float xv0 = xc[(bg     ) * 64 + xq];
                const float xv1 = xc[(bg +  8) * 64 + xq];
                const float xv2 = xc[(bg + 16) * 64 + xq];
                const float xv3 = xc[(bg + 24) * 64 + xq];
                const int wo = k * 32 + ((cg ^ (k & 3)) * 8);
                const float4 wa = *(const float4*)(wc + wo);
                const float4 wb = *(const float4*)(wc + wo + 4);
                acc[0][0] = fmaf(xv0, wa.x, acc[0][0]);
                acc[0][1] = fmaf(xv0, wa.y, acc[0][1]);
                acc[0][2] = fmaf(xv0, wa.z, acc[0][2]);
                acc[0][3] = fmaf(xv0, wa.w, acc[0][3]);
                acc[0][4] = fmaf(xv0, wb.x, acc[0][4]);
                acc[0][5] = fmaf(xv0, wb.y, acc[0][5]);
                acc[0][6] = fmaf(xv0, wb.z, acc[0][6]);
                acc[0][7] = fmaf(xv0, wb.w, acc[0][7]);
                acc[1][0] = fmaf(xv1, wa.x, acc[1][0]);
                acc[1][1] = fmaf(xv1, wa.y, acc[1][1]);
                acc[1][2] = fmaf(xv1, wa.z, acc[1][2]);
                acc[1][3] = fmaf(xv1, wa.w, acc[1][3]);
                acc[1][4] = fmaf(xv1, wb.x, acc[1][4]);
                acc[1][5] = fmaf(xv1, wb.y, acc[1][5]);
                acc[1][6] = fmaf(xv1, wb.z, acc[1][6]);
                acc[1][7] = fmaf(xv1, wb.w, acc[1][7]);
                acc[2][0] = fmaf(xv2, wa.x, acc[2][0]);
                acc[2][1] = fmaf(xv2, wa.y, acc[2][1]);
                acc[2][2] = fmaf(xv2, wa.z, acc[2][2]);
                acc[2][3] = fmaf(xv2, wa.w, acc[2][3]);
                acc[2][4] = fmaf(xv2, wb.x, acc[2][4]);
                acc[2][5] = fmaf(xv2, wb.y, acc[2][5]);
                acc[2][6] = fmaf(xv2, wb.z, acc[2][6]);
                acc[2][7] = fmaf(xv2, wb.w, acc[2][7]);
                acc[3][0] = fmaf(xv3, wa.x, acc[3][0]);
                acc[3][1] = fmaf(xv3, wa.y, acc[3][1]);
                acc[3][2] = fmaf(xv3, wa.z, acc[3][2]);
                acc[3][3] = fmaf(xv3, wa.w, acc[3][3]);
                acc[3][4] = fmaf(xv3, wb.x, acc[3][4]);
                acc[3][5] = fmaf(xv3, wb.y, acc[3][5]);
                acc[3][6] = fmaf(xv3, wb.z, acc[3][6]);
                acc[3][7] = fmaf(xv3, wb.w, acc[3][7]);
            }
            __syncthreads();   // next buf staged + all reads of cur done
            cur ^= 1;
        }

        // k-split reduce over the 8 consecutive lanes (ks) of each tile
        #pragma unroll
        for (int off = 1; off < 8; off <<= 1) {
            #pragma unroll
            for (int j = 0; j < 4; ++j)
                #pragma unroll
                for (int c = 0; c < 8; ++c)
                    acc[j][c] += __shfl_xor(acc[j][c], off, 64);
        }
        if (ks == 0) {
            float* hp = h_part + (size_t)blockIdx.x * 1024;
            #pragma unroll
            for (int j = 0; j < 4; ++j) {
                const int b = bg + 8 * j;
                #pragma unroll
                for (int c = 0; c < 8; ++c)
                    hp[b * 32 + cg * 8 + c] = acc[j][c];
            }
        }
    } else if (blockIdx.x < G1 + CPB) {
        // ---- hi-channel copy: 32 b x 307200 floats = 2457600 float4
        const int cb = blockIdx.x - G1;
        for (int i = cb * 256 + tid; i < 2457600; i += CPB * 256) {
            const int b = i / 76800;              // 76800 = 307200/4
            const int rem = i - b * 76800;
            const size_t off = (size_t)b * (6 * NN) + K3N + (size_t)rem * 4;
            *(float4*)(out + off) = *(const float4*)(x + off);
        }
    } else {
        // ---- pts1[t][j] = mean_s A[j][tess[t,s]]
        const int t = blockIdx.x - G1 - CPB;
        const int* tr = tess + t * SS;
        float s0 = 0.f, s1 = 0.f, s2 = 0.f;
        for (int s = tid; s < SS; s += 256) {
            const int idx = tr[s];
            s0 += A[idx]; s1 += A[NN + idx]; s2 += A[2 * NN + idx];
        }
        #pragma unroll
        for (int o = 32; o > 0; o >>= 1) {
            s0 += __shfl_down(s0, o, 64);
            s1 += __shfl_down(s1, o, 64);
            s2 += __shfl_down(s2, o, 64);
        }
        __shared__ float red[4 * 3];
        const int lane = tid & 63, wv = tid >> 6;
        if (lane == 0) { red[wv * 3] = s0; red[wv * 3 + 1] = s1; red[wv * 3 + 2] = s2; }
        __syncthreads();
        if (tid < 3) {
            const float s = red[tid] + red[3 + tid] + red[6 + tid] + red[9 + tid];
            pts1[t * 3 + tid] = s * (1.0f / SS);
        }
    }
}

// ---------------- KB: h-reduce + rigid params, 32 blocks (one per b)
__global__ __launch_bounds__(256) void kb_rigid(const float* __restrict__ h_part,
                                                const float* __restrict__ b1,
                                                const float* __restrict__ w2,
                                                const float* __restrict__ b2,
                                                const float* __restrict__ sz,
                                                float* __restrict__ RT) {
    const int bb = blockIdx.x;
    __shared__ float part[8][32];
    __shared__ float hsh[32];
    const int c = threadIdx.x & 31, g = threadIdx.x >> 5;
    float s = 0.f;
    for (int j = g; j < G1; j += 8) s += h_part[(size_t)j * 1024 + bb * 32 + c];
    part[g][c] = s;
    __syncthreads();
    if (threadIdx.x < 32) {
        float acc = 0.f;
        #pragma unroll
        for (int g2 = 0; g2 < 8; ++g2) acc += part[g2][threadIdx.x];
        hsh[threadIdx.x] = fmaxf(acc + b1[threadIdx.x], 0.f);
    }
    __syncthreads();
    const int t = threadIdx.x;
    if (t < TT) {
        float z[3];
        #pragma unroll
        for (int j = 0; j < 3; ++j) {
            const int col = 6 * t + 3 + j;
            float s2 = b2[col];
            #pragma unroll 8
            for (int cc = 0; cc < 32; ++cc) s2 = fmaf(hsh[cc], w2[cc * 384 + col], s2);
            z[j] = tanhf(s2);
        }
        float c0, s0, c1, s1, c2, s2v;
        sincosf(PI_F * z[0], &s0, &c0);
        sincosf(PI_F * z[1], &s1, &c1);
        sincosf(PI_F * z[2], &s2v, &c2);
        const float R00 = c0 * c1;
        const float R01 = -s0 * c2 + c0 * s1 * s2v;
        const float R02 = s0 * s2v + c0 * s1 * c2;
        const float R10 = s0 * c1;
        const float R11 = c0 * c2 + s0 * s1 * s2v;
        const float R12 = -c0 * s2v + s0 * s1 * c2;
        const float R20 = -s1;
        const float R21 = c1 * s2v;
        const float R22 = c1 * c2;
        const float szx = sz[0], szy = sz[1], szz = sz[2];
        const float cx = 0.5f * szx, cy = 0.5f * szy, cz = 0.5f * szz;
        const float T0 = z[0] * szx + cx - (cx * R00 + cy * R10 + cz * R20);
        const float T1 = z[1] * szy + cy - (cx * R01 + cy * R11 + cz * R21);
        const float T2 = z[2] * szz + cz - (cx * R02 + cy * R12 + cz * R22);
        float* o = RT + (bb * TT + t) * 12;
        o[0] = R00; o[1] = R10; o[2]  = R20; o[3]  = T0;
        o[4] = R01; o[5] = R11; o[6]  = R21; o[7]  = T1;
        o[8] = R02; o[9] = R12; o[10] = R22; o[11] = T2;
    }
}

// ---------------- K3: transform + scatter + pts2
__global__ __launch_bounds__(256) void k3_transform(const float* __restrict__ x,
                                                    const int* __restrict__ tess,
                                                    const float* __restrict__ RT,
                                                    float* __restrict__ out,
                                                    float* __restrict__ pts2) {
    const int blk = blockIdx.x;
    const int b = blk / TT, t = blk % TT;
    const float* p = RT + blk * 12;
    const float M00 = p[0], M01 = p[1], M02 = p[2], T0 = p[3];
    const float M10 = p[4], M11 = p[5], M12 = p[6], T1 = p[7];
    const float M20 = p[8], M21 = p[9], M22 = p[10], T2 = p[11];
    const float* xb = x + (size_t)b * 6 * NN;
    float* ob = out + (size_t)b * 6 * NN;
    const int* tr = tess + t * SS;
    float s0 = 0.f, s1 = 0.f, s2 = 0.f;
    for (int s = threadIdx.x; s < SS; s += 256) {
        const int idx = tr[s];
        const float x0 = xb[idx], x1 = xb[NN + idx], x2 = xb[2 * NN + idx];
        const float y0 = fmaf(M00, x0, fmaf(M01, x1, fmaf(M02, x2, T0)));
        const float y1 = fmaf(M10, x0, fmaf(M11, x1, fmaf(M12, x2, T1)));
        const float y2 = fmaf(M20, x0, fmaf(M21, x1, fmaf(M22, x2, T2)));
        ob[idx] = y0; ob[NN + idx] = y1; ob[2 * NN + idx] = y2;
        s0 += y0; s1 += y1; s2 += y2;
    }
    #pragma unroll
    for (int o = 32; o > 0; o >>= 1) {
        s0 += __shfl_down(s0, o, 64);
        s1 += __shfl_down(s1, o, 64);
        s2 += __shfl_down(s2, o, 64);
    }
    __shared__ float red[4 * 3];
    const int lane = threadIdx.x & 63, wv = threadIdx.x >> 6;
    if (lane == 0) { red[wv * 3] = s0; red[wv * 3 + 1] = s1; red[wv * 3 + 2] = s2; }
    __syncthreads();
    if (threadIdx.x < 3) {
        const float s = red[threadIdx.x] + red[3 + threadIdx.x] + red[6 + threadIdx.x] + red[9 + threadIdx.x];
        pts2[blk * 3 + threadIdx.x] = s * (1.0f / SS);
    }
}

// ---------------- K5: reg[b] = sum_{t,u} (mask[t,u]*(d1[t,u]-d2[b,t,u]))^2
__global__ __launch_bounds__(256) void k5_reg(const float* __restrict__ pts1,
                                              const float* __restrict__ pts2,
                                              const float* __restrict__ mask,
                                              float* __restrict__ out) {
    const int b = blockIdx.x;
    __shared__ float p1[TT * 3], p2[TT * 3];
    for (int i = threadIdx.x; i < TT * 3; i += 256) {
        p1[i] = pts1[i];
        p2[i] = pts2[b * TT * 3 + i];
    }
    __syncthreads();
    float acc = 0.f;
    for (int pr = threadIdx.x; pr < TT * TT; pr += 256) {
        const int t = pr >> 6, u = pr & 63;
        float dx = p1[t * 3] - p1[u * 3];
        float dy = p1[t * 3 + 1] - p1[u * 3 + 1];
        float dz = p1[t * 3 + 2] - p1[u * 3 + 2];
        const float d1 = sqrtf(dx * dx + dy * dy + dz * dz + 1e-12f);
        dx = p2[t * 3] - p2[u * 3];
        dy = p2[t * 3 + 1] - p2[u * 3 + 1];
        dz = p2[t * 3 + 2] - p2[u * 3 + 2];
        const float d2 = sqrtf(dx * dx + dy * dy + dz * dz + 1e-12f);
        const float d = mask[pr] * (d1 - d2);
        acc = fmaf(d, d, acc);
    }
    #pragma unroll
    for (int o = 32; o > 0; o >>= 1) acc += __shfl_down(acc, o, 64);
    __shared__ float red[4];
    const int lane = threadIdx.x & 63, wv = threadIdx.x >> 6;
    if (lane == 0) red[wv] = acc;
    __syncthreads();
    if (threadIdx.x == 0) {
        out[(size_t)BB * 6 * NN + b] = red[0] + red[1] + red[2] + red[3];
    }
}

extern "C" void kernel_launch(void* const* d_in, const int* in_sizes, int n_in,
                              void* d_out, int out_size, void* d_ws, size_t ws_size,
                              hipStream_t stream) {
    const float* x    = (const float*)d_in[0];
    const float* w1   = (const float*)d_in[1];
    const float* b1   = (const float*)d_in[2];
    const float* w2   = (const float*)d_in[3];
    const float* b2   = (const float*)d_in[4];
    const float* A    = (const float*)d_in[5];
    const float* mask = (const float*)d_in[6];
    const float* sz   = (const float*)d_in[7];
    const int*   tess = (const int*)d_in[8];
    float* out = (float*)d_out;
    float* ws  = (float*)d_ws;

    float* h_part = ws;                           // G1*1024 (2 MB)
    float* RT     = h_part + (size_t)G1 * 1024;   // 2048*12
    float* pts2   = RT + BB * TT * 12;            // 2048*3
    float* pts1   = pts2 + BB * TT * 3;           // 64*3

    k1_mega<<<G1 + CPB + TT, 256, 0, stream>>>(x, w1, A, tess, h_part, out, pts1);
    kb_rigid<<<BB, 256, 0, stream>>>(h_part, b1, w2, b2, sz, RT);
    k3_transform<<<BB * TT, 256, 0, stream>>>(x, tess, RT, out, pts2);
    k5_reg<<<BB, 256, 0, stream>>>(pts1, pts2, mask, out);
}

// Round 21
// 72.562 us; speedup vs baseline: 1.3960x; 1.0248x over previous
//
#include <hip/hip_runtime.h>
#include <hip/hip_bf16.h>
#include <math.h>

#define BB 32
#define NN 102400
#define TT 64
#define SS 1600
#define K3N (3 * NN)          // 307200
#define GEMSLOTS 640          // gemm index space (incl. 40 holes)
#define NSEG 75
#define SEGK 4096             // k per segment
#define SSTEP 128             // k per superstep (w LDS chunk)
#define NSS (SEGK / SSTEP)    // 32 supersteps
#define CPB 512               // hi-channel copy blocks
#define PI_F 3.14159265358979323846f

#define AS1 __attribute__((address_space(1)))
#define AS3 __attribute__((address_space(3)))

// async 16B-per-lane global->LDS DMA. LDS dest = wave-uniform base + lane*16 (HW).
__device__ __forceinline__ void gload16(const float* g, float* l) {
    __builtin_amdgcn_global_load_lds((const AS1 void*)g, (AS3 void*)l, 16, 0, 0);
}

// ---------------- K1 mega-kernel:
//   blocks [0, 640)       : GEMM1 partials, R19 few-stream partition + XCD
//       CO-LOCATION: gemm index = (seg&7) + 8*(bgp + 8*(seg>>3)) so all 8
//       bgp-blocks of a segment share one XCD (XCD = blockIdx%8 round-robin)
//       -> each w-stripe fetched from HBM once, siblings hit that XCD's L2.
//       x: wave owns ONE b-row, streamed sequentially (2400 chip streams,
//       measured 3.3 TB/s in R19). w: 16KB/superstep dbuf, rotated rows.
//   blocks [640, +CPB)    : copy channels 3..5 x->out
//   blocks [640+CPB, +TT) : pts1
__global__ __launch_bounds__(256) void k1_mega(const float* __restrict__ x,
                                               const float* __restrict__ w1,
                                               const float* __restrict__ A,
                                               const int* __restrict__ tess,
                                               float* __restrict__ h_part,
                                               float* __restrict__ out,
                                               float* __restrict__ pts1) {
    __shared__ float wls[2][SSTEP * 32];   // 2 x 16KB: [k][(c+rot)&31]
    const int tid = threadIdx.x;
    if (blockIdx.x < GEMSLOTS) {
        const int xslot = blockIdx.x & 7;
        const int rest  = blockIdx.x >> 3;
        const int bgp   = rest & 7;
        const int seg   = (rest >> 3) * 8 + xslot;   // seg % 8 == XCD slot
        if (seg >= NSEG) return;                     // hole block
        const int lane = tid & 63, wv = tid >> 6;
        const int b = bgp * 4 + wv;          // this wave's batch row
        const int K0 = seg * SEGK;
        const int rot = (lane >> 1) & 7;     // row-rotation for this lane's rows

        // w staging: 4 calls per wave; call n covers 16B-slots [(wv*4+n)*64 + lane]
        size_t gw[4]; int lw[4];
        #pragma unroll
        for (int n = 0; n < 4; ++n) {
            const int s = (wv * 4 + n) * 64 + lane;
            const int k = s >> 3, p = s & 7;
            gw[n] = (size_t)k * 32 + (((p - ((k >> 2) & 7)) & 7) * 4);
            lw[n] = (wv * 4 + n) * 256;
        }

        float acc[32];
        #pragma unroll
        for (int c = 0; c < 32; ++c) acc[c] = 0.f;

        const float* xrow = x + (size_t)b * 6 * NN + K0;

        {   // prologue: stage superstep 0 w into buffer 0
            #pragma unroll
            for (int n = 0; n < 4; ++n)
                gload16(w1 + gw[n] + (size_t)K0 * 32, &wls[0][lw[n]]);
        }
        float2 xcur = *(const float2*)(xrow + lane * 2);
        __syncthreads();   // drains vmcnt(0): buffer 0 ready

        int cur = 0;
        for (int s = 0; s < NSS; ++s) {
            float2 xnext;
            if (s + 1 < NSS) {   // next superstep's DMA + x-load fly under compute
                const int k0n = K0 + (s + 1) * SSTEP;
                const int nb = cur ^ 1;
                #pragma unroll
                for (int n = 0; n < 4; ++n)
                    gload16(w1 + gw[n] + (size_t)k0n * 32, &wls[nb][lw[n]]);
                xnext = *(const float2*)(xrow + (s + 1) * SSTEP + lane * 2);
            }
            const float* wc = wls[cur];
            #pragma unroll
            for (int kk = 0; kk < 2; ++kk) {
                const int r = lane * 2 + kk;
                const float xj = kk ? xcur.y : xcur.x;
                const float* wrow = wc + r * 32;
                #pragma unroll
                for (int q = 0; q < 8; ++q) {
                    const float4 w = *(const float4*)(wrow + ((q + rot) & 7) * 4);
                    acc[q * 4 + 0] = fmaf(xj, w.x, acc[q * 4 + 0]);
                    acc[q * 4 + 1] = fmaf(xj, w.y, acc[q * 4 + 1]);
                    acc[q * 4 + 2] = fmaf(xj, w.z, acc[q * 4 + 2]);
                    acc[q * 4 + 3] = fmaf(xj, w.w, acc[q * 4 + 3]);
                }
            }
            __syncthreads();   // next buf staged + all reads of cur done
            cur ^= 1;
            xcur = xnext;
        }

        // 64-way k-split reduce across the wave
        #pragma unroll
        for (int off = 1; off < 64; off <<= 1) {
            #pragma unroll
            for (int c = 0; c < 32; ++c)
                acc[c] += __shfl_xor(acc[c], off, 64);
        }
        if (lane == 0) {
            const int gemmid = bgp * NSEG + seg;
            float* hp = h_part + (size_t)gemmid * 128 + wv * 32;
            #pragma unroll
            for (int q = 0; q < 8; ++q) {
                float4 v;
                v.x = acc[q * 4 + 0]; v.y = acc[q * 4 + 1];
                v.z = acc[q * 4 + 2]; v.w = acc[q * 4 + 3];
                *(float4*)(hp + q * 4) = v;
            }
        }
    } else if (blockIdx.x < GEMSLOTS + CPB) {
        // ---- hi-channel copy: 32 b x 307200 floats = 2457600 float4
        const int cb = blockIdx.x - GEMSLOTS;
        for (int i = cb * 256 + tid; i < 2457600; i += CPB * 256) {
            const int b = i / 76800;              // 76800 = 307200/4
            const int rem = i - b * 76800;
            const size_t off = (size_t)b * (6 * NN) + K3N + (size_t)rem * 4;
            *(float4*)(out + off) = *(const float4*)(x + off);
        }
    } else {
        // ---- pts1[t][j] = mean_s A[j][tess[t,s]]
        const int t = blockIdx.x - GEMSLOTS - CPB;
        const int* tr = tess + t * SS;
        float s0 = 0.f, s1 = 0.f, s2 = 0.f;
        for (int s = tid; s < SS; s += 256) {
            const int idx = tr[s];
            s0 += A[idx]; s1 += A[NN + idx]; s2 += A[2 * NN + idx];
        }
        #pragma unroll
        for (int o = 32; o > 0; o >>= 1) {
            s0 += __shfl_down(s0, o, 64);
            s1 += __shfl_down(s1, o, 64);
            s2 += __shfl_down(s2, o, 64);
        }
        __shared__ float red[4 * 3];
        const int lane = tid & 63, wv = tid >> 6;
        if (lane == 0) { red[wv * 3] = s0; red[wv * 3 + 1] = s1; red[wv * 3 + 2] = s2; }
        __syncthreads();
        if (tid < 3) {
            const float s = red[tid] + red[3 + tid] + red[6 + tid] + red[9 + tid];
            pts1[t * 3 + tid] = s * (1.0f / SS);
        }
    }
}

// ---------------- KB: h-reduce + rigid params, 32 blocks (one per b)
__global__ __launch_bounds__(256) void kb_rigid(const float* __restrict__ h_part,
                                                const float* __restrict__ b1,
                                                const float* __restrict__ w2,
                                                const float* __restrict__ b2,
                                                const float* __restrict__ sz,
                                                float* __restrict__ RT) {
    const int bb = blockIdx.x;
    __shared__ float part[8][32];
    __shared__ float hsh[32];
    const int c = threadIdx.x & 31, g = threadIdx.x >> 5;
    float s = 0.f;
    const size_t base = (size_t)(bb >> 2) * NSEG * 128 + (bb & 3) * 32;
    for (int j = g; j < NSEG; j += 8) s += h_part[base + (size_t)j * 128 + c];
    part[g][c] = s;
    __syncthreads();
    if (threadIdx.x < 32) {
        float acc = 0.f;
        #pragma unroll
        for (int g2 = 0; g2 < 8; ++g2) acc += part[g2][threadIdx.x];
        hsh[threadIdx.x] = fmaxf(acc + b1[threadIdx.x], 0.f);
    }
    __syncthreads();
    const int t = threadIdx.x;
    if (t < TT) {
        float z[3];
        #pragma unroll
        for (int j = 0; j < 3; ++j) {
            const int col = 6 * t + 3 + j;
            float s2 = b2[col];
            #pragma unroll 8
            for (int cc = 0; cc < 32; ++cc) s2 = fmaf(hsh[cc], w2[cc * 384 + col], s2);
            z[j] = tanhf(s2);
        }
        float c0, s0, c1, s1, c2, s2v;
        sincosf(PI_F * z[0], &s0, &c0);
        sincosf(PI_F * z[1], &s1, &c1);
        sincosf(PI_F * z[2], &s2v, &c2);
        const float R00 = c0 * c1;
        const float R01 = -s0 * c2 + c0 * s1 * s2v;
        const float R02 = s0 * s2v + c0 * s1 * c2;
        const float R10 = s0 * c1;
        const float R11 = c0 * c2 + s0 * s1 * s2v;
        const float R12 = -c0 * s2v + s0 * s1 * c2;
        const float R20 = -s1;
        const float R21 = c1 * s2v;
        const float R22 = c1 * c2;
        const float szx = sz[0], szy = sz[1], szz = sz[2];
        const float cx = 0.5f * szx, cy = 0.5f * szy, cz = 0.5f * szz;
        const float T0 = z[0] * szx + cx - (cx * R00 + cy * R10 + cz * R20);
        const float T1 = z[1] * szy + cy - (cx * R01 + cy * R11 + cz * R21);
        const float T2 = z[2] * szz + cz - (cx * R02 + cy * R12 + cz * R22);
        float* o = RT + (bb * TT + t) * 12;
        o[0] = R00; o[1] = R10; o[2]  = R20; o[3]  = T0;
        o[4] = R01; o[5] = R11; o[6]  = R21; o[7]  = T1;
        o[8] = R02; o[9] = R12; o[10] = R22; o[11] = T2;
    }
}

// ---------------- K3: transform + scatter + pts2
__global__ __launch_bounds__(256) void k3_transform(const float* __restrict__ x,
                                                    const int* __restrict__ tess,
                                                    const float* __restrict__ RT,
                                                    float* __restrict__ out,
                                                    float* __restrict__ pts2) {
    const int blk = blockIdx.x;
    const int b = blk / TT, t = blk % TT;
    const float* p = RT + blk * 12;
    const float M00 = p[0], M01 = p[1], M02 = p[2], T0 = p[3];
    const float M10 = p[4], M11 = p[5], M12 = p[6], T1 = p[7];
    const float M20 = p[8], M21 = p[9], M22 = p[10], T2 = p[11];
    const float* xb = x + (size_t)b * 6 * NN;
    float* ob = out + (size_t)b * 6 * NN;
    const int* tr = tess + t * SS;
    float s0 = 0.f, s1 = 0.f, s2 = 0.f;
    for (int s = threadIdx.x; s < SS; s += 256) {
        const int idx = tr[s];
        const float x0 = xb[idx], x1 = xb[NN + idx], x2 = xb[2 * NN + idx];
        const float y0 = fmaf(M00, x0, fmaf(M01, x1, fmaf(M02, x2, T0)));
        const float y1 = fmaf(M10, x0, fmaf(M11, x1, fmaf(M12, x2, T1)));
        const float y2 = fmaf(M20, x0, fmaf(M21, x1, fmaf(M22, x2, T2)));
        ob[idx] = y0; ob[NN + idx] = y1; ob[2 * NN + idx] = y2;
        s0 += y0; s1 += y1; s2 += y2;
    }
    #pragma unroll
    for (int o = 32; o > 0; o >>= 1) {
        s0 += __shfl_down(s0, o, 64);
        s1 += __shfl_down(s1, o, 64);
        s2 += __shfl_down(s2, o, 64);
    }
    __shared__ float red[4 * 3];
    const int lane = threadIdx.x & 63, wv = threadIdx.x >> 6;
    if (lane == 0) { red[wv * 3] = s0; red[wv * 3 + 1] = s1; red[wv * 3 + 2] = s2; }
    __syncthreads();
    if (threadIdx.x < 3) {
        const float s = red[threadIdx.x] + red[3 + threadIdx.x] + red[6 + threadIdx.x] + red[9 + threadIdx.x];
        pts2[blk * 3 + threadIdx.x] = s * (1.0f / SS);
    }
}

// ---------------- K5: reg[b] = sum_{t,u} (mask[t,u]*(d1[t,u]-d2[b,t,u]))^2
__global__ __launch_bounds__(256) void k5_reg(const float* __restrict__ pts1,
                                              const float* __restrict__ pts2,
                                              const float* __restrict__ mask,
                                              float* __restrict__ out) {
    const int b = blockIdx.x;
    __shared__ float p1[TT * 3], p2[TT * 3];
    for (int i = threadIdx.x; i < TT * 3; i += 256) {
        p1[i] = pts1[i];
        p2[i] = pts2[b * TT * 3 + i];
    }
    __syncthreads();
    float acc = 0.f;
    for (int pr = threadIdx.x; pr < TT * TT; pr += 256) {
        const int t = pr >> 6, u = pr & 63;
        float dx = p1[t * 3] - p1[u * 3];
        float dy = p1[t * 3 + 1] - p1[u * 3 + 1];
        float dz = p1[t * 3 + 2] - p1[u * 3 + 2];
        const float d1 = sqrtf(dx * dx + dy * dy + dz * dz + 1e-12f);
        dx = p2[t * 3] - p2[u * 3];
        dy = p2[t * 3 + 1] - p2[u * 3 + 1];
        dz = p2[t * 3 + 2] - p2[u * 3 + 2];
        const float d2 = sqrtf(dx * dx + dy * dy + dz * dz + 1e-12f);
        const float d = mask[pr] * (d1 - d2);
        acc = fmaf(d, d, acc);
    }
    #pragma unroll
    for (int o = 32; o > 0; o >>= 1) acc += __shfl_down(acc, o, 64);
    __shared__ float red[4];
    const int lane = threadIdx.x & 63, wv = threadIdx.x >> 6;
    if (lane == 0) red[wv] = acc;
    __syncthreads();
    if (threadIdx.x == 0) {
        out[(size_t)BB * 6 * NN + b] = red[0] + red[1] + red[2] + red[3];
    }
}

extern "C" void kernel_launch(void* const* d_in, const int* in_sizes, int n_in,
                              void* d_out, int out_size, void* d_ws, size_t ws_size,
                              hipStream_t stream) {
    const float* x    = (const float*)d_in[0];
    const float* w1   = (const float*)d_in[1];
    const float* b1   = (const float*)d_in[2];
    const float* w2   = (const float*)d_in[3];
    const float* b2   = (const float*)d_in[4];
    const float* A    = (const float*)d_in[5];
    const float* mask = (const float*)d_in[6];
    const float* sz   = (const float*)d_in[7];
    const int*   tess = (const int*)d_in[8];
    float* out = (float*)d_out;
    float* ws  = (float*)d_ws;

    float* h_part = ws;                              // 600*128 = 76800 floats
    float* RT     = h_part + (size_t)8 * NSEG * 128; // 2048*12
    float* pts2   = RT + BB * TT * 12;               // 2048*3
    float* pts1   = pts2 + BB * TT * 3;              // 64*3

    k1_mega<<<GEMSLOTS + CPB + TT, 256, 0, stream>>>(x, w1, A, tess, h_part, out, pts1);
    kb_rigid<<<BB, 256, 0, stream>>>(h_part, b1, w2, b2, sz, RT);
    k3_transform<<<BB * TT, 256, 0, stream>>>(x, tess, RT, out, pts2);
    k5_reg<<<BB, 256, 0, stream>>>(pts1, pts2, mask, out);
}